// Round 20
// baseline (159.478 us; speedup 1.0000x reference)
//
#include <hip/hip_runtime.h>
#include <hip/hip_bf16.h>

typedef __attribute__((ext_vector_type(8))) short  s16x8;   // 8 x bf16
typedef __attribute__((ext_vector_type(4))) short  s16x4;
typedef __attribute__((ext_vector_type(4))) float  f32x4;

#define T_LEN 50000
#define S_LEN 168
#define W_IN  336
#define O_OUT 48
#define N_ROWS (T_LEN - W_IN - O_OUT + 1)   // 49617
#define N_PAD  49664                        // 776 * 64
#define NBLK   (N_PAD / 64)                 // 776

__device__ inline short f2bf(float f) {
    union { float f; unsigned u; } v; v.f = f;
    unsigned u = v.u;
    unsigned r = u + 0x7fffu + ((u >> 16) & 1u);   // RNE
    return (short)(r >> 16);
}

__device__ inline int bfpk(float lo, float hi) {   // 2xf32 -> packed 2xbf16 (RNE)
    float2 f2; f2.x = lo; f2.y = hi;
    __hip_bfloat162 h = __float22bfloat162_rn(f2);
    int r; __builtin_memcpy(&r, &h, 4);
    return r;
}

__device__ inline float readlane_f(float v, int l) {
    return __int_as_float(__builtin_amdgcn_readlane(__float_as_int(v), l));
}

__device__ inline float fast_tanh(float v) {
    float e = __expf(2.f * v);
    return 1.f - 2.f * __builtin_amdgcn_rcpf(e + 1.f);
}

// ------- scan (block 0, 1 wave) + W1/W2 preconvert (blocks 1..552) fused -------------------
// Scan: EXACT serial, 56-step chunks (168 = 3*56 -> seas(c) = w(c-3), LANE-ALIGNED).
// Schedule: iter c propagates chunk c, scans chunk c+2 using seas = w(c-1) (1-iter slack;
// Q consumed 2 iters later -> the ~250cy rcp+DPP chain spans 3 iters). ~28 instrs/iter.
#define DPP_FMA(q_, CTRL, W, RM) { \
    int t_ = __builtin_amdgcn_update_dpp(0, __float_as_int(q_), (CTRL), (RM), 0xf, true); \
    q_ = fmaf((W), __int_as_float(t_), q_); }

__global__ __launch_bounds__(256) void k_scanpre(
        const float* __restrict__ x, const float* __restrict__ level_sc,
        const float* __restrict__ seas_sc, const float* __restrict__ init_seas,
        float* __restrict__ lw, float* __restrict__ seasinit,
        const float* __restrict__ W1, const float* __restrict__ W2,
        short* __restrict__ W1T, short* __restrict__ W2T) {
    if (blockIdx.x != 0) {
        // ---- preconvert: blocks 1..552 ----
        int idx = (blockIdx.x - 1) * 256 + threadIdx.x;
        const int n1 = 352 * 352;
        const int n2 = n1 + 48 * 360;
        if (idx < n1) {
            int j = idx / 352, k = idx % 352;
            W1T[idx] = (j < 336 && k < 336) ? f2bf(W1[k * 336 + j]) : (short)0;
        } else if (idx < n2) {
            int i2 = idx - n1;
            int o = i2 / 360, k = i2 % 360;
            W2T[i2] = (k < 336) ? f2bf(W2[k * 48 + o]) : (short)0;
        }
        return;
    }
    if (threadIdx.x >= 64) return;
    int lane = threadIdx.x;          // 1 wave
    float a = 1.f / (1.f + expf(-level_sc[0]));
    float g = 1.f / (1.f + expf(-seas_sc[0]));
    float om = 1.f - a, omg = 1.f - g;

    for (int t = lane; t <= S_LEN; t += 64)
        seasinit[t] = expf(init_seas[t < S_LEN ? t : 0]);

    float lpv = x[0] / expf(init_seas[0]);
    if (lane == 0) { lw[0] = lpv; lw[1] = 1.f; }

    float om1 = om, om2v = om1 * om1, om4 = om2v * om2v, om8 = om4 * om4;
    float pl    = powf(om, (float)(lane + 1));
    float fpre  = powf(om, (float)((lane & 15) + 1));
    float fpre2 = powf(om, (float)((lane & 31) + 1));

#define SCAN(QOUT, XV, RSV) { \
    float q_ = a * (XV) * (RSV); \
    DPP_FMA(q_, 0x111, om1,  0xf); \
    DPP_FMA(q_, 0x112, om2v, 0xf); \
    DPP_FMA(q_, 0x114, om4,  0xf); \
    DPP_FMA(q_, 0x118, om8,  0xf); \
    DPP_FMA(q_, 0x142, fpre,  0xa); \
    DPP_FMA(q_, 0x143, fpre2, 0xc); \
    QOUT = q_; }

    // x slots: chunk c covers steps 1+56c .. 56+56c (8-lane overread harmless); slot = c%16
#define XLOAD(I) float xr##I = x[1 + 56 * I + lane];
    XLOAD(0) XLOAD(1) XLOAD(2) XLOAD(3) XLOAD(4) XLOAD(5) XLOAD(6) XLOAD(7)
    XLOAD(8) XLOAD(9) XLOAD(10) XLOAD(11) XLOAD(12) XLOAD(13) XLOAD(14) XLOAD(15)
#undef XLOAD

    // seeds: seas(0), seas(1) direct; wprev pre-loaded with seas(2) (init, wrapped) so
    // iter 0's scan of chunk 2 uses it; thereafter wprev = w(c-1) = seas(c+2). EXACT.
    float sc = expf(init_seas[1 + lane]);        // chunk 0: steps 1..56 (idx<=64)
    float sn = expf(init_seas[57 + lane]);       // chunk 1: steps 57..120
    int i2x = 113 + lane;
    float wprev = expf(init_seas[i2x >= S_LEN ? i2x - S_LEN : i2x]);   // seas(2)

    float Qc; SCAN(Qc, xr0, __builtin_amdgcn_rcpf(sc));
    float Qn; SCAN(Qn, xr1, __builtin_amdgcn_rcpf(sn));
    int ib = 1;   // step base of chunk c

    // iter c: propagate chunk c (seas=sc, x=slot c%16); store masked; scan chunk c+2
    // (x=slot (c+2)%16, seas=wprev); prefetch chunk c+16 into slot c%16 (clamped).
#define BODY(R, R2) { \
    float lvl = fmaf(pl, lpv, Qc); \
    lpv = readlane_f(lvl, 55); \
    float w_ = fmaf(omg, sc, (g * xr##R) * __builtin_amdgcn_rcpf(lvl)); \
    int lim = T_LEN - ib; \
    if (lane < (lim < 56 ? lim : 56)) { \
        float2 pk_; pk_.x = lvl; pk_.y = w_; \
        *(float2*)&lw[2 * (ib + lane)] = pk_; \
    } \
    float Qnew; SCAN(Qnew, xr##R2, __builtin_amdgcn_rcpf(wprev)); \
    int pidx = ib + 896 + lane; pidx = pidx > (T_LEN - 1) ? (T_LEN - 1) : pidx; \
    xr##R = x[pidx]; \
    Qc = Qn; Qn = Qnew; sc = sn; sn = wprev; wprev = w_; \
    ib += 56; }

    for (int kb = 0; kb < 55; ++kb) {   // 55*16 = 880 iters: chunks 0..879
        BODY(0,2)   BODY(1,3)   BODY(2,4)   BODY(3,5)
        BODY(4,6)   BODY(5,7)   BODY(6,8)   BODY(7,9)
        BODY(8,10)  BODY(9,11)  BODY(10,12) BODY(11,13)
        BODY(12,14) BODY(13,15) BODY(14,0)  BODY(15,1)
    }
    // 13 peeled iters: chunks 880..892 (slots 0..12); chunk 892 partial (47 steps, masked)
    BODY(0,2)   BODY(1,3)   BODY(2,4)   BODY(3,5)
    BODY(4,6)   BODY(5,7)   BODY(6,8)   BODY(7,9)
    BODY(8,10)  BODY(9,11)  BODY(10,12) BODY(11,13)
    BODY(12,14)
#undef BODY
#undef SCAN
}

// ---------------- logs + loss partials: F, llev from packed lw ------------------------------
__global__ void k_logs(const float* __restrict__ x, const float* __restrict__ lw,
                       const float* __restrict__ seasinit,
                       float* __restrict__ F, float* __restrict__ llev,
                       float* __restrict__ partials) {
    __shared__ float sm[258];
    __shared__ float red[256];
    int tid = threadIdx.x;
    int t = blockIdx.x * 256 + tid;
    float ll = 0.f;
    if (t < T_LEN) {
        float2 cur = *(const float2*)&lw[2 * t];
        int ps = t - S_LEN; if (ps < 0) ps = 0;
        float sv = (t <= S_LEN) ? seasinit[t] : lw[2 * ps + 1];
        F[t]  = __logf(x[t]) - __logf(sv);
        ll    = __logf(cur.x);
        llev[t] = ll;
    }
    sm[tid] = ll;
    if (tid < 2) {
        int te = blockIdx.x * 256 + 256 + tid;
        sm[256 + tid] = (te < T_LEN) ? __logf(lw[2 * te]) : 0.f;
    }
    __syncthreads();
    float s = 0.f;
    if (t < T_LEN - 2) {
        float d = sm[tid + 2] - 2.f * sm[tid + 1] + sm[tid];
        s = d * d;
    }
    red[tid] = s; __syncthreads();
    for (int off = 128; off > 0; off >>= 1) {
        if (tid < off) red[tid] += red[tid + off];
        __syncthreads();
    }
    if (tid == 0) partials[blockIdx.x] = red[0];
}

// ------- prep: inpbf = bf16(F - lv + noise) with COALESCED writes; labels fused ------------
__global__ __launch_bounds__(256) void k_prep(
        const float* __restrict__ noise, const float* __restrict__ F,
        const float* __restrict__ llev, short* __restrict__ inpbf,
        float* __restrict__ labels) {
    __shared__ float Flds[448];
    __shared__ float Llds[64];
    int t = threadIdx.x;
    long n0 = (long)blockIdx.x * 64;
    if (t < 112)      *(f32x4*)&Flds[t * 4] = *(const f32x4*)&F[n0 + t * 4];
    else if (t < 128) *(f32x4*)&Llds[(t - 112) * 4] = *(const f32x4*)&llev[n0 + W_IN + (t - 112) * 4];
    __syncthreads();

#pragma unroll
    for (int i = 0; i < 11; ++i) {
        int c = t + 256 * i;            // 0..2815
        int r = c / 44, kc = c - r * 44;
        int k0 = kc * 8;
        long n = n0 + r;
        int4 s = {0, 0, 0, 0};
        if (n < N_ROWS && k0 < W_IN) {
            float lv = Llds[r];
            const float* np = &noise[n * (long)W_IN + k0];
            f32x4 nz0 = *(const f32x4*)&np[0];
            f32x4 nz1 = *(const f32x4*)&np[4];
            const float* fp = &Flds[r + k0];
            s.x = bfpk(fp[0] - lv + nz0[0], fp[1] - lv + nz0[1]);
            s.y = bfpk(fp[2] - lv + nz0[2], fp[3] - lv + nz0[3]);
            s.z = bfpk(fp[4] - lv + nz1[0], fp[5] - lv + nz1[1]);
            s.w = bfpk(fp[6] - lv + nz1[2], fp[7] - lv + nz1[3]);
        }
        *(int4*)&inpbf[n * 352 + k0] = s;   // pad rows / pad cols get exact zeros
    }
#pragma unroll
    for (int i = 0; i < 3; ++i) {
        int c = t + 256 * i;            // 0..767
        int r = c / 12, cc = (c - r * 12) * 4;
        long n = n0 + r;
        if (n < N_ROWS) {
            float lv = Llds[r];
            const float* fp = &Flds[r + W_IN + cc];
            f32x4 v;
            v[0] = fp[0] - lv; v[1] = fp[1] - lv; v[2] = fp[2] - lv; v[3] = fp[3] - lv;
            *(f32x4*)&labels[n * O_OUT + cc] = v;
        }
    }
}

// ------- fused GEMM: pure-GEMM K-loop (A pre-materialized incl. -lv), R=2 ------------------
__global__ __launch_bounds__(256, 3) void k_gemm(
        const short* __restrict__ inpbf, const short* __restrict__ W1T,
        const float* __restrict__ b1, const short* __restrict__ W2T,
        const float* __restrict__ b2, const float* __restrict__ partials,
        const int* __restrict__ lvp, float* __restrict__ out,
        float* __restrict__ loss) {
    __shared__ __align__(16) short hlds[64][360];   // 46080 B
    __shared__ __align__(16) float b1lds[352];      // total 47488 B -> 3 blocks/CU

    int t = threadIdx.x, w = t >> 6, l = t & 63;
    int lm = l & 15, lq = l >> 4;
    long n0 = (long)blockIdx.x * 64;

    // loss final (block 0, wave 3)
    if (blockIdx.x == 0 && w == 3) {
        float s = partials[l] + partials[l + 64] + partials[l + 128];
        if (l < 4) s += partials[l + 192];
#pragma unroll
        for (int off = 32; off > 0; off >>= 1) s += __shfl_down(s, off, 64);
        if (l == 0) loss[0] = s / (float)(T_LEN - 2) * (float)lvp[0];
    }

    // stage b1lds (consumed only after the K-loop barrier)
    if (t < 88) {
        int i4 = t * 4;
        f32x4 v = (f32x4){0.f, 0.f, 0.f, 0.f};
        if (i4 < W_IN) v = *(const f32x4*)&b1[i4];
        *(f32x4*)&b1lds[i4] = v;
    }

    int rbase = (w >> 1) * 32;     // 0 or 32
    int jbase = (w & 1) * 176;     // 0 or 176
    const short* arow0 = inpbf + (n0 + rbase + lm) * 352 + lq * 8;
    const short* arow1 = arow0 + 16 * 352;

    f32x4 acc0[11], acc1[11];
#pragma unroll
    for (int c = 0; c < 11; ++c) { acc0[c] = (f32x4){0,0,0,0}; acc1[c] = (f32x4){0,0,0,0}; }

    const short* w1row = &W1T[(jbase + lm) * 352 + lq * 8];
#define LDW(CT, KS) (*(const s16x8*)&w1row[(CT) * 5632 + (KS) * 32])
    s16x8 af0 = LDW(0,0), af1 = LDW(1,0), af2 = LDW(2,0),
          af3 = LDW(3,0), af4 = LDW(4,0), af5 = LDW(5,0);
    s16x8 bA0 = *(const s16x8*)&arow0[0];
    s16x8 bA1 = *(const s16x8*)&arow1[0];

#define MM2(CT, AF) \
    acc0[CT] = __builtin_amdgcn_mfma_f32_16x16x32_bf16(AF, b0, acc0[CT], 0, 0, 0); \
    acc1[CT] = __builtin_amdgcn_mfma_f32_16x16x32_bf16(AF, bb1, acc1[CT], 0, 0, 0);

#define KSTEP_R(KS, A0,A1,A2,A3,A4,A5) { \
    s16x8 b0 = bA0, bb1 = bA1; \
    if ((KS) < 10) { \
        bA0 = *(const s16x8*)&arow0[((KS)+1) * 32]; \
        bA1 = *(const s16x8*)&arow1[((KS)+1) * 32]; \
    } \
    MM2(0, A0)   A0 = LDW(6, (KS)); \
    MM2(1, A1)   A1 = LDW(7, (KS)); \
    MM2(2, A2)   A2 = LDW(8, (KS)); \
    MM2(3, A3)   A3 = LDW(9, (KS)); \
    MM2(4, A4)   A4 = LDW(10, (KS)); \
    MM2(5, A5)   if ((KS) < 10) A5 = LDW(0, (KS)+1); \
    MM2(6, A0)   if ((KS) < 10) A0 = LDW(1, (KS)+1); \
    MM2(7, A1)   if ((KS) < 10) A1 = LDW(2, (KS)+1); \
    MM2(8, A2)   if ((KS) < 10) A2 = LDW(3, (KS)+1); \
    MM2(9, A3)   if ((KS) < 10) A3 = LDW(4, (KS)+1); \
    MM2(10, A4)  if ((KS) < 10) A4 = LDW(5, (KS)+1); \
}

    KSTEP_R(0,  af0,af1,af2,af3,af4,af5)
    KSTEP_R(1,  af5,af0,af1,af2,af3,af4)
    KSTEP_R(2,  af4,af5,af0,af1,af2,af3)
    KSTEP_R(3,  af3,af4,af5,af0,af1,af2)
    KSTEP_R(4,  af2,af3,af4,af5,af0,af1)
    KSTEP_R(5,  af1,af2,af3,af4,af5,af0)
    KSTEP_R(6,  af0,af1,af2,af3,af4,af5)
    KSTEP_R(7,  af5,af0,af1,af2,af3,af4)
    KSTEP_R(8,  af4,af5,af0,af1,af2,af3)
    KSTEP_R(9,  af3,af4,af5,af0,af1,af2)
    KSTEP_R(10, af2,af3,af4,af5,af0,af1)
#undef KSTEP_R
#undef MM2
#undef LDW

    __syncthreads();

    // epilogue 1: h = tanh(acc + b1) -> hlds
#pragma unroll
    for (int ct = 0; ct < 11; ++ct) {
        f32x4 b1q = *(f32x4*)&b1lds[jbase + ct * 16 + lq * 4];
        int2 p0, p1;
        p0.x = bfpk(fast_tanh(acc0[ct][0] + b1q[0]), fast_tanh(acc0[ct][1] + b1q[1]));
        p0.y = bfpk(fast_tanh(acc0[ct][2] + b1q[2]), fast_tanh(acc0[ct][3] + b1q[3]));
        p1.x = bfpk(fast_tanh(acc1[ct][0] + b1q[0]), fast_tanh(acc1[ct][1] + b1q[1]));
        p1.y = bfpk(fast_tanh(acc1[ct][2] + b1q[2]), fast_tanh(acc1[ct][3] + b1q[3]));
        *(int2*)&hlds[rbase + lm][jbase + ct * 16 + lq * 4]      = p0;
        *(int2*)&hlds[rbase + 16 + lm][jbase + ct * 16 + lq * 4] = p1;
    }
    __syncthreads();

    // gemm2
    f32x4 a2[3];
    a2[0] = (f32x4){0,0,0,0}; a2[1] = (f32x4){0,0,0,0}; a2[2] = (f32x4){0,0,0,0};
#pragma unroll
    for (int ks = 0; ks < 11; ++ks) {
        s16x8 hf = *(s16x8*)&hlds[w * 16 + lm][ks * 32 + lq * 8];
#pragma unroll
        for (int ct = 0; ct < 3; ++ct) {
            s16x8 bf2 = *(const s16x8*)&W2T[(ct * 16 + lm) * 360 + ks * 32 + lq * 8];
            a2[ct] = __builtin_amdgcn_mfma_f32_16x16x32_bf16(hf, bf2, a2[ct], 0, 0, 0);
        }
    }
    int rloc = w * 16 + lq * 4;
#pragma unroll
    for (int ct = 0; ct < 3; ++ct) {
        float b2v = b2[ct * 16 + lm];
#pragma unroll
        for (int r = 0; r < 4; ++r) {
            long row = n0 + rloc + r;
            if (row < N_ROWS) out[row * O_OUT + ct * 16 + lm] = a2[ct][r] + b2v;
        }
    }
}

extern "C" void kernel_launch(void* const* d_in, const int* in_sizes, int n_in,
                              void* d_out, int out_size, void* d_ws, size_t ws_size,
                              hipStream_t stream) {
    const float* x         = (const float*)d_in[0];
    const float* noise     = (const float*)d_in[1];
    const float* level_sc  = (const float*)d_in[2];
    const float* seas_sc   = (const float*)d_in[3];
    const float* init_seas = (const float*)d_in[4];
    const float* W1        = (const float*)d_in[5];
    const float* b1        = (const float*)d_in[6];
    const float* W2        = (const float*)d_in[7];
    const float* b2        = (const float*)d_in[8];
    const int*   lvp       = (const int*)d_in[11];

    float* out    = (float*)d_out;
    float* labels = out + (long)N_ROWS * O_OUT;
    float* loss   = labels + (long)N_ROWS * O_OUT;

    float* wsf      = (float*)d_ws;
    float* lw       = wsf;                 // 2*50000 packed {level,w} (reserve 100096)
    float* seasinit = wsf + 100096;        // 169 (reserve 192)
    float* F        = wsf + 100288;        // 50000 (reserve 50176)
    float* llev     = wsf + 150464;        // 50000 (reserve 50048)
    float* partials = wsf + 200512;        // 196 (reserve 256)
    short* W1T      = (short*)(wsf + 200768);       // 352*352 bf16
    short* W2T      = W1T + 352 * 352;              // 48*360 bf16
    short* inpbf    = (short*)(wsf + 271360);       // N_PAD*352 bf16 (~35 MB)

    k_scanpre<<<553, 256, 0, stream>>>(x, level_sc, seas_sc, init_seas, lw, seasinit,
                                       W1, W2, W1T, W2T);
    k_logs<<<196, 256, 0, stream>>>(x, lw, seasinit, F, llev, partials);
    k_prep<<<NBLK, 256, 0, stream>>>(noise, F, llev, inpbf, labels);
    k_gemm<<<NBLK, 256, 0, stream>>>(inpbf, W1T, b1, W2T, b2, partials, lvp, out, loss);
}

// Round 21
// 144.305 us; speedup vs baseline: 1.1051x; 1.1051x over previous
//
#include <hip/hip_runtime.h>
#include <hip/hip_bf16.h>

typedef __attribute__((ext_vector_type(8))) short  s16x8;   // 8 x bf16
typedef __attribute__((ext_vector_type(4))) short  s16x4;
typedef __attribute__((ext_vector_type(4))) float  f32x4;

#define T_LEN 50000
#define S_LEN 168
#define W_IN  336
#define O_OUT 48
#define N_ROWS (T_LEN - W_IN - O_OUT + 1)   // 49617
#define N_PAD  49664                        // 776 * 64
#define NBLK   (N_PAD / 64)                 // 776

__device__ inline short f2bf(float f) {
    union { float f; unsigned u; } v; v.f = f;
    unsigned u = v.u;
    unsigned r = u + 0x7fffu + ((u >> 16) & 1u);   // RNE
    return (short)(r >> 16);
}

__device__ inline int bfpk(float lo, float hi) {   // 2xf32 -> packed 2xbf16 (RNE)
    float2 f2; f2.x = lo; f2.y = hi;
    __hip_bfloat162 h = __float22bfloat162_rn(f2);
    int r; __builtin_memcpy(&r, &h, 4);
    return r;
}

__device__ inline float readlane_f(float v, int l) {
    return __int_as_float(__builtin_amdgcn_readlane(__float_as_int(v), l));
}

__device__ inline float fast_tanh(float v) {
    float e = __expf(2.f * v);
    return 1.f - 2.f * __builtin_amdgcn_rcpf(e + 1.f);
}

// ---- pre-convert W1 -> W1T bf16 [352][352] (zero-padded), W2 -> W2T [48][360] -------------
__global__ void k_preconvert(const float* __restrict__ W1, const float* __restrict__ W2,
                             short* __restrict__ W1T, short* __restrict__ W2T) {
    int idx = blockIdx.x * 256 + threadIdx.x;
    const int n1 = 352 * 352;
    const int n2 = n1 + 48 * 360;
    if (idx < n1) {
        int j = idx / 352, k = idx % 352;
        W1T[idx] = (j < 336 && k < 336) ? f2bf(W1[k * 336 + j]) : (short)0;
    } else if (idx < n2) {
        int i2 = idx - n1;
        int o = i2 / 360, k = i2 % 360;
        W2T[i2] = (k < 336) ? f2bf(W2[k * 48 + o]) : (short)0;
    }
}

// ------- scan: R16-exact — ringless, seas via 2x ds_bpermute, 64-step chunks ---------------
#define DPP_FMA(q_, CTRL, W, RM) { \
    int t_ = __builtin_amdgcn_update_dpp(0, __float_as_int(q_), (CTRL), (RM), 0xf, true); \
    q_ = fmaf((W), __int_as_float(t_), q_); }

__global__ void k_scan(const float* __restrict__ x, const float* __restrict__ level_sc,
                       const float* __restrict__ seas_sc, const float* __restrict__ init_seas,
                       float* __restrict__ lw, float* __restrict__ seasinit) {
    int lane = threadIdx.x;          // 64 threads, 1 wave
    float a = 1.f / (1.f + expf(-level_sc[0]));
    float g = 1.f / (1.f + expf(-seas_sc[0]));
    float om = 1.f - a, omg = 1.f - g;

    for (int t = lane; t <= S_LEN; t += 64)
        seasinit[t] = expf(init_seas[t < S_LEN ? t : 0]);

    float lpv = x[0] / expf(init_seas[0]);
    if (lane == 0) { lw[0] = lpv; lw[1] = 1.f; }

    float om1 = om, om2v = om1 * om1, om4 = om2v * om2v, om8 = om4 * om4;
    float pl    = powf(om, (float)(lane + 1));
    float fpre  = powf(om, (float)((lane & 15) + 1));
    float fpre2 = powf(om, (float)((lane & 31) + 1));

    int  idx4 = ((lane + 24) & 63) << 2;   // bpermute byte addr
    bool lowj = (lane < 40);

#define SCAN(QOUT, XV, RSV) { \
    float q_ = a * (XV) * (RSV); \
    DPP_FMA(q_, 0x111, om1,  0xf); \
    DPP_FMA(q_, 0x112, om2v, 0xf); \
    DPP_FMA(q_, 0x114, om4,  0xf); \
    DPP_FMA(q_, 0x118, om8,  0xf); \
    DPP_FMA(q_, 0x142, fpre,  0xa); \
    DPP_FMA(q_, 0x143, fpre2, 0xc); \
    QOUT = q_; }

#define XLOAD(I) float xr##I = x[1 + 64 * I + lane];
    XLOAD(0) XLOAD(1) XLOAD(2) XLOAD(3) XLOAD(4) XLOAD(5) XLOAD(6) XLOAD(7)
    XLOAD(8) XLOAD(9) XLOAD(10) XLOAD(11) XLOAD(12) XLOAD(13) XLOAD(14) XLOAD(15)
#undef XLOAD

    float sW = expf(init_seas[1 + lane]);
    float sN = expf(init_seas[65 + lane]);
    int t105 = 105 + lane;
    float wPrev = expf(init_seas[t105 >= S_LEN ? 0 : t105]);
    float Qcur; SCAN(Qcur, xr0, __builtin_amdgcn_rcpf(sW));
    int ib = 1;

#define BODY(R, RN, CLAMP) { \
    float lvl = fmaf(pl, lpv, Qcur); \
    lpv = readlane_f(lvl, 63); \
    float w_ = fmaf(omg, sW, (g * xr##R) * __builtin_amdgcn_rcpf(lvl)); \
    float2 pk_; pk_.x = lvl; pk_.y = w_; \
    *(float2*)&lw[2 * (ib + lane)] = pk_; \
    int tA_ = __builtin_amdgcn_ds_bpermute(idx4, __float_as_int(wPrev)); \
    int tB_ = __builtin_amdgcn_ds_bpermute(idx4, __float_as_int(w_)); \
    float sNN_ = lowj ? __int_as_float(tA_) : __int_as_float(tB_); \
    float Qn_; SCAN(Qn_, xr##RN, __builtin_amdgcn_rcpf(sN)); \
    int pidx = ib + 1024 + lane; \
    if (CLAMP) pidx = pidx > (T_LEN - 1) ? (T_LEN - 1) : pidx; \
    xr##R = x[pidx]; \
    Qcur = Qn_; sW = sN; sN = sNN_; wPrev = w_; \
    ib += 64; }

    for (int kb = 0; kb < 47; ++kb) {
        BODY(0,1,0)  BODY(1,2,0)  BODY(2,3,0)  BODY(3,4,0)
        BODY(4,5,0)  BODY(5,6,0)  BODY(6,7,0)  BODY(7,8,0)
        BODY(8,9,0)  BODY(9,10,0) BODY(10,11,0) BODY(11,12,0)
        BODY(12,13,0) BODY(13,14,0) BODY(14,15,0) BODY(15,0,0)
    }
    BODY(0,1,0)  BODY(1,2,0)  BODY(2,3,0)  BODY(3,4,0)
    BODY(4,5,0)  BODY(5,6,0)  BODY(6,7,0)  BODY(7,8,0)
    BODY(8,9,0)  BODY(9,10,0) BODY(10,11,0) BODY(11,12,0)
    BODY(12,13,0)
    BODY(13,14,1) BODY(14,15,1) BODY(15,0,1)
    BODY(0,1,1)  BODY(1,2,1)  BODY(2,3,1)  BODY(3,4,1)
    BODY(4,5,1)  BODY(5,6,1)  BODY(6,7,1)  BODY(7,8,1)
    BODY(8,9,1)  BODY(9,10,1) BODY(10,11,1) BODY(11,12,1)
#undef BODY

    {   // chunk 780
        float lvl = fmaf(pl, lpv, Qcur);
        lpv = readlane_f(lvl, 63);
        float w_ = fmaf(omg, sW, (g * xr12) * __builtin_amdgcn_rcpf(lvl));
        float2 pk_; pk_.x = lvl; pk_.y = w_;
        *(float2*)&lw[2 * (49921 + lane)] = pk_;
    }
    {   // chunk 781 (lanes 0..14)
        float Qn_; SCAN(Qn_, xr13, __builtin_amdgcn_rcpf(sN));
        float lvl = fmaf(pl, lpv, Qn_);
        if (lane < 15) {
            float w_ = fmaf(omg, sN, (g * xr13) * __builtin_amdgcn_rcpf(lvl));
            float2 pk_; pk_.x = lvl; pk_.y = w_;
            *(float2*)&lw[2 * (49985 + lane)] = pk_;
        }
    }
#undef SCAN
}

// ---------------- logs + loss partials: F, llev from packed lw ------------------------------
__global__ void k_logs(const float* __restrict__ x, const float* __restrict__ lw,
                       const float* __restrict__ seasinit,
                       float* __restrict__ F, float* __restrict__ llev,
                       float* __restrict__ partials) {
    __shared__ float sm[258];
    __shared__ float red[256];
    int tid = threadIdx.x;
    int t = blockIdx.x * 256 + tid;
    float ll = 0.f;
    if (t < T_LEN) {
        float2 cur = *(const float2*)&lw[2 * t];
        int ps = t - S_LEN; if (ps < 0) ps = 0;
        float sv = (t <= S_LEN) ? seasinit[t] : lw[2 * ps + 1];
        F[t]  = __logf(x[t]) - __logf(sv);
        ll    = __logf(cur.x);
        llev[t] = ll;
    }
    sm[tid] = ll;
    if (tid < 2) {
        int te = blockIdx.x * 256 + 256 + tid;
        sm[256 + tid] = (te < T_LEN) ? __logf(lw[2 * te]) : 0.f;
    }
    __syncthreads();
    float s = 0.f;
    if (t < T_LEN - 2) {
        float d = sm[tid + 2] - 2.f * sm[tid + 1] + sm[tid];
        s = d * d;
    }
    red[tid] = s; __syncthreads();
    for (int off = 128; off > 0; off >>= 1) {
        if (tid < off) red[tid] += red[tid + off];
        __syncthreads();
    }
    if (tid == 0) partials[blockIdx.x] = red[0];
}

// ------- fused prep+GEMM: inp tile built in LDS (no inpbf round-trip); labels fused --------
__global__ __launch_bounds__(256, 3) void k_gemm(
        const float* __restrict__ noise, const float* __restrict__ F,
        const float* __restrict__ llev, const short* __restrict__ W1T,
        const float* __restrict__ b1, const short* __restrict__ W2T,
        const float* __restrict__ b2, const float* __restrict__ partials,
        const int* __restrict__ lvp, float* __restrict__ out,
        float* __restrict__ labels, float* __restrict__ loss) {
    __shared__ __align__(16) char  uni[46080];   // phase1: inp[64][352]; phase2: hlds[64][360]
    __shared__ __align__(16) float Flds[448];
    __shared__ __align__(16) float Llds[64];
    __shared__ __align__(16) float b1lds[352];   // total 49536 B -> 3 blocks/CU
    short (*inp)[352]  = (short(*)[352])uni;
    short (*hlds)[360] = (short(*)[360])uni;

    int t = threadIdx.x, w = t >> 6, l = t & 63;
    int lm = l & 15, lq = l >> 4;
    long n0 = (long)blockIdx.x * 64;

    // loss final (block 0, wave 3)
    if (blockIdx.x == 0 && w == 3) {
        float s = partials[l] + partials[l + 64] + partials[l + 128];
        if (l < 4) s += partials[l + 192];
#pragma unroll
        for (int off = 32; off > 0; off >>= 1) s += __shfl_down(s, off, 64);
        if (l == 0) loss[0] = s / (float)(T_LEN - 2) * (float)lvp[0];
    }

    // stage Flds / Llds / b1lds
    if (t < 112)      *(f32x4*)&Flds[t * 4] = *(const f32x4*)&F[n0 + t * 4];
    else if (t < 128) *(f32x4*)&Llds[(t - 112) * 4] = *(const f32x4*)&llev[n0 + W_IN + (t - 112) * 4];
    else if (t < 216) {
        int i4 = (t - 128) * 4;
        f32x4 v = (f32x4){0.f, 0.f, 0.f, 0.f};
        if (i4 < W_IN) v = *(const f32x4*)&b1[i4];
        *(f32x4*)&b1lds[i4] = v;
    }
    __syncthreads();

    // build inp[64][352] bf16 in LDS (coalesced noise reads; pad rows/cols exact zeros)
#pragma unroll
    for (int i = 0; i < 11; ++i) {
        int c = t + 256 * i;            // 0..2815
        int r = c / 44, kc = c - r * 44;
        int k0 = kc * 8;
        long n = n0 + r;
        int4 s = {0, 0, 0, 0};
        if (n < N_ROWS && k0 < W_IN) {
            float lv = Llds[r];
            const float* np = &noise[n * (long)W_IN + k0];
            f32x4 nz0 = *(const f32x4*)&np[0];
            f32x4 nz1 = *(const f32x4*)&np[4];
            const float* fp = &Flds[r + k0];
            s.x = bfpk(fp[0] - lv + nz0[0], fp[1] - lv + nz0[1]);
            s.y = bfpk(fp[2] - lv + nz0[2], fp[3] - lv + nz0[3]);
            s.z = bfpk(fp[4] - lv + nz1[0], fp[5] - lv + nz1[1]);
            s.w = bfpk(fp[6] - lv + nz1[2], fp[7] - lv + nz1[3]);
        }
        *(int4*)&inp[r][k0] = s;
    }
    __syncthreads();

    int rbase = (w >> 1) * 32;     // 0 or 32
    int jbase = (w & 1) * 176;     // 0 or 176
    const short* arow0 = &inp[rbase + lm][lq * 8];
    const short* arow1 = &inp[rbase + 16 + lm][lq * 8];

    f32x4 acc0[11], acc1[11];
#pragma unroll
    for (int c = 0; c < 11; ++c) { acc0[c] = (f32x4){0,0,0,0}; acc1[c] = (f32x4){0,0,0,0}; }

    const short* w1row = &W1T[(jbase + lm) * 352 + lq * 8];
#define LDW(CT, KS) (*(const s16x8*)&w1row[(CT) * 5632 + (KS) * 32])
    s16x8 af0 = LDW(0,0), af1 = LDW(1,0), af2 = LDW(2,0),
          af3 = LDW(3,0), af4 = LDW(4,0), af5 = LDW(5,0);
    s16x8 bA0 = *(const s16x8*)&arow0[0];
    s16x8 bA1 = *(const s16x8*)&arow1[0];

#define MM2(CT, AF) \
    acc0[CT] = __builtin_amdgcn_mfma_f32_16x16x32_bf16(AF, b0, acc0[CT], 0, 0, 0); \
    acc1[CT] = __builtin_amdgcn_mfma_f32_16x16x32_bf16(AF, bb1, acc1[CT], 0, 0, 0);

// 6-deep rotating af bank (W1 global); A operand from LDS, prefetched 1 ks ahead.
#define KSTEP_R(KS, A0,A1,A2,A3,A4,A5) { \
    s16x8 b0 = bA0, bb1 = bA1; \
    if ((KS) < 10) { \
        bA0 = *(const s16x8*)&arow0[((KS)+1) * 32]; \
        bA1 = *(const s16x8*)&arow1[((KS)+1) * 32]; \
    } \
    MM2(0, A0)   A0 = LDW(6, (KS)); \
    MM2(1, A1)   A1 = LDW(7, (KS)); \
    MM2(2, A2)   A2 = LDW(8, (KS)); \
    MM2(3, A3)   A3 = LDW(9, (KS)); \
    MM2(4, A4)   A4 = LDW(10, (KS)); \
    MM2(5, A5)   if ((KS) < 10) A5 = LDW(0, (KS)+1); \
    MM2(6, A0)   if ((KS) < 10) A0 = LDW(1, (KS)+1); \
    MM2(7, A1)   if ((KS) < 10) A1 = LDW(2, (KS)+1); \
    MM2(8, A2)   if ((KS) < 10) A2 = LDW(3, (KS)+1); \
    MM2(9, A3)   if ((KS) < 10) A3 = LDW(4, (KS)+1); \
    MM2(10, A4)  if ((KS) < 10) A4 = LDW(5, (KS)+1); \
}

    KSTEP_R(0,  af0,af1,af2,af3,af4,af5)
    KSTEP_R(1,  af5,af0,af1,af2,af3,af4)
    KSTEP_R(2,  af4,af5,af0,af1,af2,af3)
    KSTEP_R(3,  af3,af4,af5,af0,af1,af2)
    KSTEP_R(4,  af2,af3,af4,af5,af0,af1)
    KSTEP_R(5,  af1,af2,af3,af4,af5,af0)
    KSTEP_R(6,  af0,af1,af2,af3,af4,af5)
    KSTEP_R(7,  af5,af0,af1,af2,af3,af4)
    KSTEP_R(8,  af4,af5,af0,af1,af2,af3)
    KSTEP_R(9,  af3,af4,af5,af0,af1,af2)
    KSTEP_R(10, af2,af3,af4,af5,af0,af1)
#undef KSTEP_R
#undef MM2
#undef LDW

    __syncthreads();   // all inp (uni) reads complete -> safe to overwrite as hlds

    // epilogue 1: h = tanh(acc + b1) -> hlds (aliases inp region)
#pragma unroll
    for (int ct = 0; ct < 11; ++ct) {
        f32x4 b1q = *(f32x4*)&b1lds[jbase + ct * 16 + lq * 4];
        int2 p0, p1;
        p0.x = bfpk(fast_tanh(acc0[ct][0] + b1q[0]), fast_tanh(acc0[ct][1] + b1q[1]));
        p0.y = bfpk(fast_tanh(acc0[ct][2] + b1q[2]), fast_tanh(acc0[ct][3] + b1q[3]));
        p1.x = bfpk(fast_tanh(acc1[ct][0] + b1q[0]), fast_tanh(acc1[ct][1] + b1q[1]));
        p1.y = bfpk(fast_tanh(acc1[ct][2] + b1q[2]), fast_tanh(acc1[ct][3] + b1q[3]));
        *(int2*)&hlds[rbase + lm][jbase + ct * 16 + lq * 4]      = p0;
        *(int2*)&hlds[rbase + 16 + lm][jbase + ct * 16 + lq * 4] = p1;
    }
    __syncthreads();

    // gemm2: each wave does 16 rows
    f32x4 a2[3];
    a2[0] = (f32x4){0,0,0,0}; a2[1] = (f32x4){0,0,0,0}; a2[2] = (f32x4){0,0,0,0};
#pragma unroll
    for (int ks = 0; ks < 11; ++ks) {
        s16x8 hf = *(s16x8*)&hlds[w * 16 + lm][ks * 32 + lq * 8];
#pragma unroll
        for (int ct = 0; ct < 3; ++ct) {
            s16x8 bf2 = *(const s16x8*)&W2T[(ct * 16 + lm) * 360 + ks * 32 + lq * 8];
            a2[ct] = __builtin_amdgcn_mfma_f32_16x16x32_bf16(hf, bf2, a2[ct], 0, 0, 0);
        }
    }
    int rloc = w * 16 + lq * 4;
#pragma unroll
    for (int ct = 0; ct < 3; ++ct) {
        float b2v = b2[ct * 16 + lm];
#pragma unroll
        for (int r = 0; r < 4; ++r) {
            long row = n0 + rloc + r;
            if (row < N_ROWS) out[row * O_OUT + ct * 16 + lm] = a2[ct][r] + b2v;
        }
    }

    // labels (coalesced, from still-resident Flds/Llds)
#pragma unroll
    for (int i = 0; i < 3; ++i) {
        int c = t + 256 * i;            // 0..767
        int r = c / 12, cc = (c - r * 12) * 4;
        long n = n0 + r;
        if (n < N_ROWS) {
            float lv = Llds[r];
            const float* fp = &Flds[r + W_IN + cc];
            f32x4 v;
            v[0] = fp[0] - lv; v[1] = fp[1] - lv; v[2] = fp[2] - lv; v[3] = fp[3] - lv;
            *(f32x4*)&labels[n * O_OUT + cc] = v;
        }
    }
}

extern "C" void kernel_launch(void* const* d_in, const int* in_sizes, int n_in,
                              void* d_out, int out_size, void* d_ws, size_t ws_size,
                              hipStream_t stream) {
    const float* x         = (const float*)d_in[0];
    const float* noise     = (const float*)d_in[1];
    const float* level_sc  = (const float*)d_in[2];
    const float* seas_sc   = (const float*)d_in[3];
    const float* init_seas = (const float*)d_in[4];
    const float* W1        = (const float*)d_in[5];
    const float* b1        = (const float*)d_in[6];
    const float* W2        = (const float*)d_in[7];
    const float* b2        = (const float*)d_in[8];
    const int*   lvp       = (const int*)d_in[11];

    float* out    = (float*)d_out;
    float* labels = out + (long)N_ROWS * O_OUT;
    float* loss   = labels + (long)N_ROWS * O_OUT;

    float* wsf      = (float*)d_ws;
    float* lw       = wsf;                 // 2*50000 packed {level,w} (reserve 100096)
    float* seasinit = wsf + 100096;        // 169 (reserve 192)
    float* F        = wsf + 100288;        // 50000 (reserve 50176)
    float* llev     = wsf + 150464;        // 50000 (reserve 50048)
    float* partials = wsf + 200512;        // 196 (reserve 256)
    short* W1T      = (short*)(wsf + 200768);       // 352*352 bf16
    short* W2T      = W1T + 352 * 352;              // 48*360 bf16

    k_preconvert<<<552, 256, 0, stream>>>(W1, W2, W1T, W2T);
    k_scan<<<1, 64, 0, stream>>>(x, level_sc, seas_sc, init_seas, lw, seasinit);
    k_logs<<<196, 256, 0, stream>>>(x, lw, seasinit, F, llev, partials);
    k_gemm<<<NBLK, 256, 0, stream>>>(noise, F, llev, W1T, b1, W2T, b2,
                                     partials, lvp, out, labels, loss);
}

// Round 22
// 141.617 us; speedup vs baseline: 1.1261x; 1.0190x over previous
//
#include <hip/hip_runtime.h>
#include <hip/hip_bf16.h>

typedef __attribute__((ext_vector_type(8))) short  s16x8;   // 8 x bf16
typedef __attribute__((ext_vector_type(4))) short  s16x4;
typedef __attribute__((ext_vector_type(4))) float  f32x4;

#define T_LEN 50000
#define S_LEN 168
#define W_IN  336
#define O_OUT 48
#define N_ROWS (T_LEN - W_IN - O_OUT + 1)   // 49617
#define N_PAD  49664                        // 776 * 64
#define NBLK   (N_PAD / 64)                 // 776

__device__ inline short f2bf(float f) {
    union { float f; unsigned u; } v; v.f = f;
    unsigned u = v.u;
    unsigned r = u + 0x7fffu + ((u >> 16) & 1u);   // RNE
    return (short)(r >> 16);
}

__device__ inline int bfpk(float lo, float hi) {   // 2xf32 -> packed 2xbf16 (RNE)
    float2 f2; f2.x = lo; f2.y = hi;
    __hip_bfloat162 h = __float22bfloat162_rn(f2);
    int r; __builtin_memcpy(&r, &h, 4);
    return r;
}

__device__ inline float readlane_f(float v, int l) {
    return __int_as_float(__builtin_amdgcn_readlane(__float_as_int(v), l));
}

__device__ inline float fast_tanh(float v) {
    float e = __expf(2.f * v);
    return 1.f - 2.f * __builtin_amdgcn_rcpf(e + 1.f);
}

// ---- pre-convert W1 -> W1T bf16 [352][352] (zero-padded), W2 -> W2T [48][360] -------------
__global__ void k_preconvert(const float* __restrict__ W1, const float* __restrict__ W2,
                             short* __restrict__ W1T, short* __restrict__ W2T) {
    int idx = blockIdx.x * 256 + threadIdx.x;
    const int n1 = 352 * 352;
    const int n2 = n1 + 48 * 360;
    if (idx < n1) {
        int j = idx / 352, k = idx % 352;
        W1T[idx] = (j < 336 && k < 336) ? f2bf(W1[k * 336 + j]) : (short)0;
    } else if (idx < n2) {
        int i2 = idx - n1;
        int o = i2 / 360, k = i2 % 360;
        W2T[i2] = (k < 336) ? f2bf(W2[k * 48 + o]) : (short)0;
    }
}

// ------- scan: R16-exact — ringless, seas via 2x ds_bpermute, 64-step chunks ---------------
#define DPP_FMA(q_, CTRL, W, RM) { \
    int t_ = __builtin_amdgcn_update_dpp(0, __float_as_int(q_), (CTRL), (RM), 0xf, true); \
    q_ = fmaf((W), __int_as_float(t_), q_); }

__global__ void k_scan(const float* __restrict__ x, const float* __restrict__ level_sc,
                       const float* __restrict__ seas_sc, const float* __restrict__ init_seas,
                       float* __restrict__ lw, float* __restrict__ seasinit) {
    int lane = threadIdx.x;          // 64 threads, 1 wave
    float a = 1.f / (1.f + expf(-level_sc[0]));
    float g = 1.f / (1.f + expf(-seas_sc[0]));
    float om = 1.f - a, omg = 1.f - g;

    for (int t = lane; t <= S_LEN; t += 64)
        seasinit[t] = expf(init_seas[t < S_LEN ? t : 0]);

    float lpv = x[0] / expf(init_seas[0]);
    if (lane == 0) { lw[0] = lpv; lw[1] = 1.f; }

    float om1 = om, om2v = om1 * om1, om4 = om2v * om2v, om8 = om4 * om4;
    float pl    = powf(om, (float)(lane + 1));
    float fpre  = powf(om, (float)((lane & 15) + 1));
    float fpre2 = powf(om, (float)((lane & 31) + 1));

    int  idx4 = ((lane + 24) & 63) << 2;   // bpermute byte addr
    bool lowj = (lane < 40);

#define SCAN(QOUT, XV, RSV) { \
    float q_ = a * (XV) * (RSV); \
    DPP_FMA(q_, 0x111, om1,  0xf); \
    DPP_FMA(q_, 0x112, om2v, 0xf); \
    DPP_FMA(q_, 0x114, om4,  0xf); \
    DPP_FMA(q_, 0x118, om8,  0xf); \
    DPP_FMA(q_, 0x142, fpre,  0xa); \
    DPP_FMA(q_, 0x143, fpre2, 0xc); \
    QOUT = q_; }

#define XLOAD(I) float xr##I = x[1 + 64 * I + lane];
    XLOAD(0) XLOAD(1) XLOAD(2) XLOAD(3) XLOAD(4) XLOAD(5) XLOAD(6) XLOAD(7)
    XLOAD(8) XLOAD(9) XLOAD(10) XLOAD(11) XLOAD(12) XLOAD(13) XLOAD(14) XLOAD(15)
#undef XLOAD

    float sW = expf(init_seas[1 + lane]);
    float sN = expf(init_seas[65 + lane]);
    int t105 = 105 + lane;
    float wPrev = expf(init_seas[t105 >= S_LEN ? 0 : t105]);
    float Qcur; SCAN(Qcur, xr0, __builtin_amdgcn_rcpf(sW));
    int ib = 1;

#define BODY(R, RN, CLAMP) { \
    float lvl = fmaf(pl, lpv, Qcur); \
    lpv = readlane_f(lvl, 63); \
    float w_ = fmaf(omg, sW, (g * xr##R) * __builtin_amdgcn_rcpf(lvl)); \
    float2 pk_; pk_.x = lvl; pk_.y = w_; \
    *(float2*)&lw[2 * (ib + lane)] = pk_; \
    int tA_ = __builtin_amdgcn_ds_bpermute(idx4, __float_as_int(wPrev)); \
    int tB_ = __builtin_amdgcn_ds_bpermute(idx4, __float_as_int(w_)); \
    float sNN_ = lowj ? __int_as_float(tA_) : __int_as_float(tB_); \
    float Qn_; SCAN(Qn_, xr##RN, __builtin_amdgcn_rcpf(sN)); \
    int pidx = ib + 1024 + lane; \
    if (CLAMP) pidx = pidx > (T_LEN - 1) ? (T_LEN - 1) : pidx; \
    xr##R = x[pidx]; \
    Qcur = Qn_; sW = sN; sN = sNN_; wPrev = w_; \
    ib += 64; }

    for (int kb = 0; kb < 47; ++kb) {
        BODY(0,1,0)  BODY(1,2,0)  BODY(2,3,0)  BODY(3,4,0)
        BODY(4,5,0)  BODY(5,6,0)  BODY(6,7,0)  BODY(7,8,0)
        BODY(8,9,0)  BODY(9,10,0) BODY(10,11,0) BODY(11,12,0)
        BODY(12,13,0) BODY(13,14,0) BODY(14,15,0) BODY(15,0,0)
    }
    BODY(0,1,0)  BODY(1,2,0)  BODY(2,3,0)  BODY(3,4,0)
    BODY(4,5,0)  BODY(5,6,0)  BODY(6,7,0)  BODY(7,8,0)
    BODY(8,9,0)  BODY(9,10,0) BODY(10,11,0) BODY(11,12,0)
    BODY(12,13,0)
    BODY(13,14,1) BODY(14,15,1) BODY(15,0,1)
    BODY(0,1,1)  BODY(1,2,1)  BODY(2,3,1)  BODY(3,4,1)
    BODY(4,5,1)  BODY(5,6,1)  BODY(6,7,1)  BODY(7,8,1)
    BODY(8,9,1)  BODY(9,10,1) BODY(10,11,1) BODY(11,12,1)
#undef BODY

    {   // chunk 780
        float lvl = fmaf(pl, lpv, Qcur);
        lpv = readlane_f(lvl, 63);
        float w_ = fmaf(omg, sW, (g * xr12) * __builtin_amdgcn_rcpf(lvl));
        float2 pk_; pk_.x = lvl; pk_.y = w_;
        *(float2*)&lw[2 * (49921 + lane)] = pk_;
    }
    {   // chunk 781 (lanes 0..14)
        float Qn_; SCAN(Qn_, xr13, __builtin_amdgcn_rcpf(sN));
        float lvl = fmaf(pl, lpv, Qn_);
        if (lane < 15) {
            float w_ = fmaf(omg, sN, (g * xr13) * __builtin_amdgcn_rcpf(lvl));
            float2 pk_; pk_.x = lvl; pk_.y = w_;
            *(float2*)&lw[2 * (49985 + lane)] = pk_;
        }
    }
#undef SCAN
}

// ---------------- logs + loss partials: F, llev from packed lw ------------------------------
__global__ void k_logs(const float* __restrict__ x, const float* __restrict__ lw,
                       const float* __restrict__ seasinit,
                       float* __restrict__ F, float* __restrict__ llev,
                       float* __restrict__ partials) {
    __shared__ float sm[258];
    __shared__ float red[256];
    int tid = threadIdx.x;
    int t = blockIdx.x * 256 + tid;
    float ll = 0.f;
    if (t < T_LEN) {
        float2 cur = *(const float2*)&lw[2 * t];
        int ps = t - S_LEN; if (ps < 0) ps = 0;
        float sv = (t <= S_LEN) ? seasinit[t] : lw[2 * ps + 1];
        F[t]  = __logf(x[t]) - __logf(sv);
        ll    = __logf(cur.x);
        llev[t] = ll;
    }
    sm[tid] = ll;
    if (tid < 2) {
        int te = blockIdx.x * 256 + 256 + tid;
        sm[256 + tid] = (te < T_LEN) ? __logf(lw[2 * te]) : 0.f;
    }
    __syncthreads();
    float s = 0.f;
    if (t < T_LEN - 2) {
        float d = sm[tid + 2] - 2.f * sm[tid + 1] + sm[tid];
        s = d * d;
    }
    red[tid] = s; __syncthreads();
    for (int off = 128; off > 0; off >>= 1) {
        if (tid < off) red[tid] += red[tid + off];
        __syncthreads();
    }
    if (tid == 0) partials[blockIdx.x] = red[0];
}

// ------- fused prep+GEMM: inp tile in LDS (stride 360, bank-spread); no bA prefetch regs ---
__global__ __launch_bounds__(256, 3) void k_gemm(
        const float* __restrict__ noise, const float* __restrict__ F,
        const float* __restrict__ llev, const short* __restrict__ W1T,
        const float* __restrict__ b1, const short* __restrict__ W2T,
        const float* __restrict__ b2, const float* __restrict__ partials,
        const int* __restrict__ lvp, float* __restrict__ out,
        float* __restrict__ labels, float* __restrict__ loss) {
    __shared__ __align__(16) char  uni[46080];   // phase1: inp[64][360]; phase2: hlds[64][360]
    __shared__ __align__(16) float Flds[448];
    __shared__ __align__(16) float Llds[64];
    __shared__ __align__(16) float b1lds[352];   // total 49536 B -> 3 blocks/CU
    short (*inp)[360]  = (short(*)[360])uni;     // stride 720B = 20 banks mod 32 (2-way max)
    short (*hlds)[360] = (short(*)[360])uni;

    int t = threadIdx.x, w = t >> 6, l = t & 63;
    int lm = l & 15, lq = l >> 4;
    long n0 = (long)blockIdx.x * 64;

    // loss final (block 0, wave 3)
    if (blockIdx.x == 0 && w == 3) {
        float s = partials[l] + partials[l + 64] + partials[l + 128];
        if (l < 4) s += partials[l + 192];
#pragma unroll
        for (int off = 32; off > 0; off >>= 1) s += __shfl_down(s, off, 64);
        if (l == 0) loss[0] = s / (float)(T_LEN - 2) * (float)lvp[0];
    }

    // stage Flds / Llds / b1lds
    if (t < 112)      *(f32x4*)&Flds[t * 4] = *(const f32x4*)&F[n0 + t * 4];
    else if (t < 128) *(f32x4*)&Llds[(t - 112) * 4] = *(const f32x4*)&llev[n0 + W_IN + (t - 112) * 4];
    else if (t < 216) {
        int i4 = (t - 128) * 4;
        f32x4 v = (f32x4){0.f, 0.f, 0.f, 0.f};
        if (i4 < W_IN) v = *(const f32x4*)&b1[i4];
        *(f32x4*)&b1lds[i4] = v;
    }
    __syncthreads();

    // build inp[64][360] bf16 in LDS (cols 0..351 written; 352..359 never read in phase 1)
#pragma unroll
    for (int i = 0; i < 11; ++i) {
        int c = t + 256 * i;            // 0..2815
        int r = c / 44, kc = c - r * 44;
        int k0 = kc * 8;
        long n = n0 + r;
        int4 s = {0, 0, 0, 0};
        if (n < N_ROWS && k0 < W_IN) {
            float lv = Llds[r];
            const float* np = &noise[n * (long)W_IN + k0];
            f32x4 nz0 = *(const f32x4*)&np[0];
            f32x4 nz1 = *(const f32x4*)&np[4];
            const float* fp = &Flds[r + k0];
            s.x = bfpk(fp[0] - lv + nz0[0], fp[1] - lv + nz0[1]);
            s.y = bfpk(fp[2] - lv + nz0[2], fp[3] - lv + nz0[3]);
            s.z = bfpk(fp[4] - lv + nz1[0], fp[5] - lv + nz1[1]);
            s.w = bfpk(fp[6] - lv + nz1[2], fp[7] - lv + nz1[3]);
        }
        *(int4*)&inp[r][k0] = s;
    }
    __syncthreads();

    int rbase = (w >> 1) * 32;     // 0 or 32
    int jbase = (w & 1) * 176;     // 0 or 176
    const short* arow0 = &inp[rbase + lm][lq * 8];
    const short* arow1 = &inp[rbase + 16 + lm][lq * 8];

    f32x4 acc0[11], acc1[11];
#pragma unroll
    for (int c = 0; c < 11; ++c) { acc0[c] = (f32x4){0,0,0,0}; acc1[c] = (f32x4){0,0,0,0}; }

    const short* w1row = &W1T[(jbase + lm) * 352 + lq * 8];
#define LDW(CT, KS) (*(const s16x8*)&w1row[(CT) * 5632 + (KS) * 32])
    s16x8 af0 = LDW(0,0), af1 = LDW(1,0), af2 = LDW(2,0),
          af3 = LDW(3,0), af4 = LDW(4,0), af5 = LDW(5,0);

#define MM2(CT, AF) \
    acc0[CT] = __builtin_amdgcn_mfma_f32_16x16x32_bf16(AF, b0, acc0[CT], 0, 0, 0); \
    acc1[CT] = __builtin_amdgcn_mfma_f32_16x16x32_bf16(AF, bb1, acc1[CT], 0, 0, 0);

// A operand read directly from LDS per KSTEP (covered by 22 MFMAs); 6-deep af bank for W1.
#define KSTEP_R(KS, A0,A1,A2,A3,A4,A5) { \
    s16x8 b0  = *(const s16x8*)&arow0[(KS) * 32]; \
    s16x8 bb1 = *(const s16x8*)&arow1[(KS) * 32]; \
    MM2(0, A0)   A0 = LDW(6, (KS)); \
    MM2(1, A1)   A1 = LDW(7, (KS)); \
    MM2(2, A2)   A2 = LDW(8, (KS)); \
    MM2(3, A3)   A3 = LDW(9, (KS)); \
    MM2(4, A4)   A4 = LDW(10, (KS)); \
    MM2(5, A5)   if ((KS) < 10) A5 = LDW(0, (KS)+1); \
    MM2(6, A0)   if ((KS) < 10) A0 = LDW(1, (KS)+1); \
    MM2(7, A1)   if ((KS) < 10) A1 = LDW(2, (KS)+1); \
    MM2(8, A2)   if ((KS) < 10) A2 = LDW(3, (KS)+1); \
    MM2(9, A3)   if ((KS) < 10) A3 = LDW(4, (KS)+1); \
    MM2(10, A4)  if ((KS) < 10) A4 = LDW(5, (KS)+1); \
}

    KSTEP_R(0,  af0,af1,af2,af3,af4,af5)
    KSTEP_R(1,  af5,af0,af1,af2,af3,af4)
    KSTEP_R(2,  af4,af5,af0,af1,af2,af3)
    KSTEP_R(3,  af3,af4,af5,af0,af1,af2)
    KSTEP_R(4,  af2,af3,af4,af5,af0,af1)
    KSTEP_R(5,  af1,af2,af3,af4,af5,af0)
    KSTEP_R(6,  af0,af1,af2,af3,af4,af5)
    KSTEP_R(7,  af5,af0,af1,af2,af3,af4)
    KSTEP_R(8,  af4,af5,af0,af1,af2,af3)
    KSTEP_R(9,  af3,af4,af5,af0,af1,af2)
    KSTEP_R(10, af2,af3,af4,af5,af0,af1)
#undef KSTEP_R
#undef MM2
#undef LDW

    __syncthreads();   // all inp (uni) reads complete -> safe to overwrite as hlds

    // epilogue 1: h = tanh(acc + b1) -> hlds (aliases inp region)
#pragma unroll
    for (int ct = 0; ct < 11; ++ct) {
        f32x4 b1q = *(f32x4*)&b1lds[jbase + ct * 16 + lq * 4];
        int2 p0, p1;
        p0.x = bfpk(fast_tanh(acc0[ct][0] + b1q[0]), fast_tanh(acc0[ct][1] + b1q[1]));
        p0.y = bfpk(fast_tanh(acc0[ct][2] + b1q[2]), fast_tanh(acc0[ct][3] + b1q[3]));
        p1.x = bfpk(fast_tanh(acc1[ct][0] + b1q[0]), fast_tanh(acc1[ct][1] + b1q[1]));
        p1.y = bfpk(fast_tanh(acc1[ct][2] + b1q[2]), fast_tanh(acc1[ct][3] + b1q[3]));
        *(int2*)&hlds[rbase + lm][jbase + ct * 16 + lq * 4]      = p0;
        *(int2*)&hlds[rbase + 16 + lm][jbase + ct * 16 + lq * 4] = p1;
    }
    __syncthreads();

    // gemm2: each wave does 16 rows (hlds cols 336..351 = tanh(0+0)=0 exact zeros)
    f32x4 a2[3];
    a2[0] = (f32x4){0,0,0,0}; a2[1] = (f32x4){0,0,0,0}; a2[2] = (f32x4){0,0,0,0};
#pragma unroll
    for (int ks = 0; ks < 11; ++ks) {
        s16x8 hf = *(s16x8*)&hlds[w * 16 + lm][ks * 32 + lq * 8];
#pragma unroll
        for (int ct = 0; ct < 3; ++ct) {
            s16x8 bf2 = *(const s16x8*)&W2T[(ct * 16 + lm) * 360 + ks * 32 + lq * 8];
            a2[ct] = __builtin_amdgcn_mfma_f32_16x16x32_bf16(hf, bf2, a2[ct], 0, 0, 0);
        }
    }
    int rloc = w * 16 + lq * 4;
#pragma unroll
    for (int ct = 0; ct < 3; ++ct) {
        float b2v = b2[ct * 16 + lm];
#pragma unroll
        for (int r = 0; r < 4; ++r) {
            long row = n0 + rloc + r;
            if (row < N_ROWS) out[row * O_OUT + ct * 16 + lm] = a2[ct][r] + b2v;
        }
    }

    // labels (coalesced, from still-resident Flds/Llds)
#pragma unroll
    for (int i = 0; i < 3; ++i) {
        int c = t + 256 * i;            // 0..767
        int r = c / 12, cc = (c - r * 12) * 4;
        long n = n0 + r;
        if (n < N_ROWS) {
            float lv = Llds[r];
            const float* fp = &Flds[r + W_IN + cc];
            f32x4 v;
            v[0] = fp[0] - lv; v[1] = fp[1] - lv; v[2] = fp[2] - lv; v[3] = fp[3] - lv;
            *(f32x4*)&labels[n * O_OUT + cc] = v;
        }
    }
}

extern "C" void kernel_launch(void* const* d_in, const int* in_sizes, int n_in,
                              void* d_out, int out_size, void* d_ws, size_t ws_size,
                              hipStream_t stream) {
    const float* x         = (const float*)d_in[0];
    const float* noise     = (const float*)d_in[1];
    const float* level_sc  = (const float*)d_in[2];
    const float* seas_sc   = (const float*)d_in[3];
    const float* init_seas = (const float*)d_in[4];
    const float* W1        = (const float*)d_in[5];
    const float* b1        = (const float*)d_in[6];
    const float* W2        = (const float*)d_in[7];
    const float* b2        = (const float*)d_in[8];
    const int*   lvp       = (const int*)d_in[11];

    float* out    = (float*)d_out;
    float* labels = out + (long)N_ROWS * O_OUT;
    float* loss   = labels + (long)N_ROWS * O_OUT;

    float* wsf      = (float*)d_ws;
    float* lw       = wsf;                 // 2*50000 packed {level,w} (reserve 100096)
    float* seasinit = wsf + 100096;        // 169 (reserve 192)
    float* F        = wsf + 100288;        // 50000 (reserve 50176)
    float* llev     = wsf + 150464;        // 50000 (reserve 50048)
    float* partials = wsf + 200512;        // 196 (reserve 256)
    short* W1T      = (short*)(wsf + 200768);       // 352*352 bf16
    short* W2T      = W1T + 352 * 352;              // 48*360 bf16

    k_preconvert<<<552, 256, 0, stream>>>(W1, W2, W1T, W2T);
    k_scan<<<1, 64, 0, stream>>>(x, level_sc, seas_sc, init_seas, lw, seasinit);
    k_logs<<<196, 256, 0, stream>>>(x, lw, seasinit, F, llev, partials);
    k_gemm<<<NBLK, 256, 0, stream>>>(noise, F, llev, W1T, b1, W2T, b2,
                                     partials, lvp, out, labels, loss);
}